// Round 5
// baseline (1467.446 us; speedup 1.0000x reference)
//
#include <hip/hip_runtime.h>

#define D 64
#define NG 512

// ---------------- edge pass: weighted in-degree (dst) + out-degree count (src) ----------------
__global__ __launch_bounds__(256) void k_edge_deg(const int* __restrict__ src,
                                                  const int* __restrict__ dst,
                                                  const float* __restrict__ w,
                                                  float* __restrict__ deg,
                                                  int* __restrict__ cnt, int E) {
    int e = blockIdx.x * 256 + threadIdx.x;
    if (e < E) {
        atomicAdd(&deg[dst[e]], w[e]);   // GCN norm uses weighted in-degree
        atomicAdd(&cnt[src[e]], 1);      // CSC: edges grouped by src
    }
}

// ---------------- node pass: dinv = 1/sqrt(deg+1), graph counts ----------------
__global__ __launch_bounds__(256) void k_node_dinv(const float* __restrict__ deg,
                                                   float* __restrict__ dinv,
                                                   const int* __restrict__ batch,
                                                   int* __restrict__ gcnt, int N) {
    int n = blockIdx.x * 256 + threadIdx.x;
    if (n < N) {
        // full precision: dinv multiplies into every edge coeff of all 3 layers
        dinv[n] = 1.0f / sqrtf(deg[n] + 1.0f);
        atomicAdd(&gcnt[batch[n]], 1);
    }
}

// ---------------- exclusive scan of counts (3 kernels) ----------------
__global__ __launch_bounds__(256) void k_scan1(const int* __restrict__ cnt,
                                               int* __restrict__ rp,
                                               int* __restrict__ bsums, int N) {
    __shared__ int s[256];
    int t = threadIdx.x;
    int i = blockIdx.x * 256 + t;
    int v = (i < N) ? cnt[i] : 0;
    s[t] = v;
    __syncthreads();
    for (int off = 1; off < 256; off <<= 1) {
        int a = (t >= off) ? s[t - off] : 0;
        __syncthreads();
        s[t] += a;
        __syncthreads();
    }
    if (i < N) rp[i] = s[t] - v;            // block-local exclusive
    if (t == 255) bsums[blockIdx.x] = s[255];
}

__global__ __launch_bounds__(512) void k_scan2(int* __restrict__ bsums, int nb) {
    __shared__ int s[512];
    int t = threadIdx.x;
    int v = (t < nb) ? bsums[t] : 0;
    s[t] = v;
    __syncthreads();
    for (int off = 1; off < 512; off <<= 1) {
        int a = (t >= off) ? s[t - off] : 0;
        __syncthreads();
        s[t] += a;
        __syncthreads();
    }
    if (t < nb) bsums[t] = s[t] - v;        // exclusive block offsets
}

__global__ __launch_bounds__(256) void k_scan3(int* __restrict__ rp,
                                               const int* __restrict__ bsums, int N) {
    int i = blockIdx.x * 256 + threadIdx.x;
    if (i < N) rp[i] += bsums[blockIdx.x];
}

// ---------------- CSC fill: per-src list of packed (dst, norm) ----------------
__global__ __launch_bounds__(256) void k_fill(const int* __restrict__ src,
                                              const int* __restrict__ dst,
                                              const float* __restrict__ w,
                                              const float* __restrict__ dinv,
                                              const int* __restrict__ rp,
                                              int* __restrict__ fill,
                                              int2* __restrict__ pack, int E) {
    int e = blockIdx.x * 256 + threadIdx.x;
    if (e < E) {
        int s0 = src[e], d0 = dst[e];
        int pos = rp[s0] + atomicAdd(&fill[s0], 1);
        pack[pos] = make_int2(d0, __float_as_int(dinv[s0] * w[e] * dinv[d0]));
    }
}

// ---------------- GEMM + epilogue: hW = reluA(A)@W ; init = bias + dinv^2 * hW ----------------
// Row-block-local, so `init` may alias A (in-place): A rows are staged to LDS
// and synced before any write.
template <int RELUA>
__global__ __launch_bounds__(256) void k_gemm(const float* __restrict__ A,
                                              const float* __restrict__ W,
                                              const float* __restrict__ bias,
                                              const float* __restrict__ dinv,
                                              float* __restrict__ hW,
                                              float* __restrict__ init, int N) {
    __shared__ float sW[64 * 64];
    __shared__ float sA[64 * 64];
    int t = threadIdx.x;
    int rb = blockIdx.x * 64;
    #pragma unroll
    for (int i = 0; i < 16; i++) sW[t + 256 * i] = W[t + 256 * i];
    #pragma unroll
    for (int i = 0; i < 16; i++) {
        int idx = t + 256 * i;
        int r = rb + (idx >> 6);
        float v = (r < N) ? A[(size_t)r * D + (idx & 63)] : 0.0f;
        sA[idx] = RELUA ? fmaxf(v, 0.0f) : v;
    }
    __syncthreads();
    int tx = t & 15, ty = t >> 4;           // 16x16 threads, 4x4 micro-tile
    float acc[4][4] = {};
    #pragma unroll
    for (int k = 0; k < 64; k++) {
        float4 wv = *(const float4*)&sW[k * 64 + tx * 4];
        float h0 = sA[(ty * 4 + 0) * 64 + k];
        float h1 = sA[(ty * 4 + 1) * 64 + k];
        float h2 = sA[(ty * 4 + 2) * 64 + k];
        float h3 = sA[(ty * 4 + 3) * 64 + k];
        acc[0][0] += h0 * wv.x; acc[0][1] += h0 * wv.y; acc[0][2] += h0 * wv.z; acc[0][3] += h0 * wv.w;
        acc[1][0] += h1 * wv.x; acc[1][1] += h1 * wv.y; acc[1][2] += h1 * wv.z; acc[1][3] += h1 * wv.w;
        acc[2][0] += h2 * wv.x; acc[2][1] += h2 * wv.y; acc[2][2] += h2 * wv.z; acc[2][3] += h2 * wv.w;
        acc[3][0] += h3 * wv.x; acc[3][1] += h3 * wv.y; acc[3][2] += h3 * wv.z; acc[3][3] += h3 * wv.w;
    }
    float4 bv = *(const float4*)&bias[tx * 4];
    #pragma unroll
    for (int i = 0; i < 4; i++) {
        int r = rb + ty * 4 + i;
        if (r < N) {
            float4 o = make_float4(acc[i][0], acc[i][1], acc[i][2], acc[i][3]);
            *(float4*)&hW[(size_t)r * D + tx * 4] = o;
            float dv = dinv[r];
            float s2 = dv * dv;
            float4 z;
            z.x = bv.x + s2 * o.x; z.y = bv.y + s2 * o.y;
            z.z = bv.z + s2 * o.z; z.w = bv.w + s2 * o.w;
            *(float4*)&init[(size_t)r * D + tx * 4] = z;
        }
    }
}

// ---------------- scatter: for each src node, stream its row, atomic-add to dsts ----------------
// one wave per src node; lane = channel. Read side fully streaming; atomics
// are fire-and-forget (no dependent-load latency chain).
__global__ __launch_bounds__(256) void k_scatter(const float* __restrict__ hW,
                                                 const int* __restrict__ rp,
                                                 const int* __restrict__ cnt,
                                                 const int2* __restrict__ pack,
                                                 float* __restrict__ hout, int N) {
    int lane = threadIdx.x & 63;
    int n = blockIdx.x * 4 + (threadIdx.x >> 6);
    if (n >= N) return;
    float my = hW[(size_t)n * D + lane];
    int r0 = rp[n], c = cnt[n];
    int e = 0;
    for (; e + 4 <= c; e += 4) {
        int2 p0 = pack[r0 + e + 0];
        int2 p1 = pack[r0 + e + 1];
        int2 p2 = pack[r0 + e + 2];
        int2 p3 = pack[r0 + e + 3];
        atomicAdd(&hout[(size_t)p0.x * D + lane], __int_as_float(p0.y) * my);
        atomicAdd(&hout[(size_t)p1.x * D + lane], __int_as_float(p1.y) * my);
        atomicAdd(&hout[(size_t)p2.x * D + lane], __int_as_float(p2.y) * my);
        atomicAdd(&hout[(size_t)p3.x * D + lane], __int_as_float(p3.y) * my);
    }
    for (; e < c; e++) {
        int2 p = pack[r0 + e];
        atomicAdd(&hout[(size_t)p.x * D + lane], __int_as_float(p.y) * my);
    }
}

// ---------------- readout MLP + graph-sum ----------------
__global__ __launch_bounds__(256) void k_readout(const float* __restrict__ h2,
                                                 const float* __restrict__ RW1,
                                                 const float* __restrict__ Rb1,
                                                 const float* __restrict__ RW2,
                                                 const float* __restrict__ Rb2,
                                                 const int* __restrict__ batch,
                                                 float* __restrict__ gsum, int N) {
    __shared__ float sh[4][64];
    int lane = threadIdx.x & 63;
    int widx = threadIdx.x >> 6;
    int n = blockIdx.x * 4 + widx;
    if (n >= N) return;                   // all LDS traffic is wave-internal
    sh[widx][lane] = h2[(size_t)n * D + lane];
    int unit = lane & 31, half = lane >> 5;
    float m = 0.0f;
    #pragma unroll
    for (int j = 0; j < 32; j++) {
        int cc = half * 32 + j;
        m += sh[widx][cc] * RW1[cc * 32 + unit];
    }
    m += __shfl_xor(m, 32);               // combine the two cc-halves
    m += Rb1[unit];
    m = fmaxf(m, 0.0f);
    float y = m * RW2[unit];
    #pragma unroll
    for (int off = 16; off >= 1; off >>= 1) y += __shfl_xor(y, off);
    if (lane == 0) atomicAdd(&gsum[batch[n]], y + Rb2[0]);
}

// ---------------- scatter-mean finalize ----------------
__global__ __launch_bounds__(256) void k_final(const float* __restrict__ gsum,
                                               const int* __restrict__ gcnt,
                                               float* __restrict__ out, int G) {
    int g = blockIdx.x * 256 + threadIdx.x;
    if (g < G) out[g] = gsum[g] / fmaxf((float)gcnt[g], 1.0f);
}

extern "C" void kernel_launch(void* const* d_in, const int* in_sizes, int n_in,
                              void* d_out, int out_size, void* d_ws, size_t ws_size,
                              hipStream_t stream) {
    const float* x     = (const float*)d_in[0];
    const int*   ei    = (const int*)d_in[1];
    const float* ea    = (const float*)d_in[2];
    const int*   batch = (const int*)d_in[3];
    const float* W0 = (const float*)d_in[4];
    const float* b0 = (const float*)d_in[5];
    const float* W1 = (const float*)d_in[6];
    const float* b1 = (const float*)d_in[7];
    const float* W2 = (const float*)d_in[8];
    const float* b2 = (const float*)d_in[9];
    const float* RW1 = (const float*)d_in[10];
    const float* Rb1 = (const float*)d_in[11];
    const float* RW2 = (const float*)d_in[12];
    const float* Rb2 = (const float*)d_in[13];

    const int N = in_sizes[0] / D;        // 100000
    const int E = in_sizes[1] / 2;        // 1200000
    const int G = out_size;               // 512
    const int* src = ei;
    const int* dst = ei + E;

    // ---- workspace layout ----
    char* p = (char*)d_ws;
    // zero-init region (one memset): deg, cnt, fill, gsum, gcnt
    float* deg   = (float*)p;             p += (size_t)N * 4;
    int*   cnt   = (int*)p;               p += (size_t)N * 4;
    int*   fill  = (int*)p;               p += (size_t)N * 4;
    float* gsum  = (float*)p;             p += (size_t)NG * 4;
    int*   gcnt  = (int*)p;               p += (size_t)NG * 4;
    size_t zbytes = (size_t)(3 * N + 2 * NG) * 4;
    // no-init region
    float* dinv  = (float*)p;             p += (size_t)N * 4;
    int*   rp    = (int*)p;               p += (size_t)N * 4;
    int*   bsums = (int*)p;               p += (size_t)512 * 4;
    int2*  pack  = (int2*)p;              p += (size_t)E * 8;   // exact, no padding
    float* hW    = (float*)p;             p += (size_t)N * D * 4;
    float* buf   = (float*)p;             p += (size_t)N * D * 4;  // activations / init / agg out

    hipMemsetAsync(d_ws, 0, zbytes, stream);

    int ebl = (E + 255) / 256;
    int nbl = (N + 255) / 256;            // 391
    k_edge_deg<<<ebl, 256, 0, stream>>>(src, dst, ea, deg, cnt, E);
    k_node_dinv<<<nbl, 256, 0, stream>>>(deg, dinv, batch, gcnt, N);
    k_scan1<<<nbl, 256, 0, stream>>>(cnt, rp, bsums, N);
    k_scan2<<<1, 512, 0, stream>>>(bsums, nbl);
    k_scan3<<<nbl, 256, 0, stream>>>(rp, bsums, N);
    k_fill<<<ebl, 256, 0, stream>>>(src, dst, ea, dinv, rp, fill, pack, E);

    int gemm_bl = (N + 63) / 64;          // 1563
    int node_bl = (N + 3) / 4;            // 25000

    // layer 0: buf = b0 + s2*(x@W0); scatter adds neighbor terms
    k_gemm<0><<<gemm_bl, 256, 0, stream>>>(x, W0, b0, dinv, hW, buf, N);
    k_scatter<<<node_bl, 256, 0, stream>>>(hW, rp, cnt, pack, buf, N);
    // layer 1: relu fused into A-load; init in-place over buf (row-block local)
    k_gemm<1><<<gemm_bl, 256, 0, stream>>>(buf, W1, b1, dinv, hW, buf, N);
    k_scatter<<<node_bl, 256, 0, stream>>>(hW, rp, cnt, pack, buf, N);
    // layer 2 (no relu after)
    k_gemm<1><<<gemm_bl, 256, 0, stream>>>(buf, W2, b2, dinv, hW, buf, N);
    k_scatter<<<node_bl, 256, 0, stream>>>(hW, rp, cnt, pack, buf, N);

    k_readout<<<node_bl, 256, 0, stream>>>(buf, RW1, Rb1, RW2, Rb2, batch, gsum, N);
    k_final<<<(G + 255) / 256, 256, 0, stream>>>(gsum, gcnt, (float*)d_out, G);
}

// Round 11
// 871.298 us; speedup vs baseline: 1.6842x; 1.6842x over previous
//
#include <hip/hip_runtime.h>

#define D 64
#define NG 512

// ---------------- edge pass: degree + per-node in-edge histogram (by dst) ----------------
__global__ __launch_bounds__(256) void k_edge_deg(const int* __restrict__ src,
                                                  const int* __restrict__ dst,
                                                  const float* __restrict__ w,
                                                  float* __restrict__ deg,
                                                  int* __restrict__ cnt, int E) {
    int e = blockIdx.x * 256 + threadIdx.x;
    if (e < E) {
        int d = dst[e];
        atomicAdd(&deg[d], w[e]);
        atomicAdd(&cnt[d], 1);
    }
}

// ---------------- node pass: dinv = 1/sqrt(deg+1), graph counts ----------------
__global__ __launch_bounds__(256) void k_node_dinv(const float* __restrict__ deg,
                                                   float* __restrict__ dinv,
                                                   const int* __restrict__ batch,
                                                   int* __restrict__ gcnt, int N) {
    int n = blockIdx.x * 256 + threadIdx.x;
    if (n < N) {
        // full precision: dinv multiplies into every edge coeff of all 3 layers
        dinv[n] = 1.0f / sqrtf(deg[n] + 1.0f);
        atomicAdd(&gcnt[batch[n]], 1);
    }
}

// ---------------- exclusive scan of padded counts (3 kernels) ----------------
// scan input = (cnt+15)&~15: each node's CSR slice is a whole number of
// 16-edge groups; pad slots are pre-zeroed (col=0, val=0 -> contributes 0).
__global__ __launch_bounds__(256) void k_scan1(const int* __restrict__ cnt,
                                               int* __restrict__ rp,
                                               int* __restrict__ bsums, int N) {
    __shared__ int s[256];
    int t = threadIdx.x;
    int i = blockIdx.x * 256 + t;
    int v = (i < N) ? ((cnt[i] + 15) & ~15) : 0;
    s[t] = v;
    __syncthreads();
    for (int off = 1; off < 256; off <<= 1) {
        int a = (t >= off) ? s[t - off] : 0;
        __syncthreads();
        s[t] += a;
        __syncthreads();
    }
    if (i < N) rp[i] = s[t] - v;            // block-local exclusive
    if (t == 255) bsums[blockIdx.x] = s[255];
}

__global__ __launch_bounds__(512) void k_scan2(int* __restrict__ bsums, int nb) {
    __shared__ int s[512];
    int t = threadIdx.x;
    int v = (t < nb) ? bsums[t] : 0;
    s[t] = v;
    __syncthreads();
    for (int off = 1; off < 512; off <<= 1) {
        int a = (t >= off) ? s[t - off] : 0;
        __syncthreads();
        s[t] += a;
        __syncthreads();
    }
    if (t < nb) bsums[t] = s[t] - v;        // exclusive block offsets
}

__global__ __launch_bounds__(256) void k_scan3(int* __restrict__ rp,
                                               const int* __restrict__ bsums, int N) {
    int i = blockIdx.x * 256 + threadIdx.x;
    if (i < N) rp[i] += bsums[blockIdx.x];
}

// ---------------- CSR fill: packed (src, norm) int2, grouped by dst ----------------
__global__ __launch_bounds__(256) void k_fill(const int* __restrict__ src,
                                              const int* __restrict__ dst,
                                              const float* __restrict__ w,
                                              const float* __restrict__ dinv,
                                              const int* __restrict__ rp,
                                              int* __restrict__ fill,
                                              int2* __restrict__ pack, int E) {
    int e = blockIdx.x * 256 + threadIdx.x;
    if (e < E) {
        int s0 = src[e], d0 = dst[e];
        int pos = rp[d0] + atomicAdd(&fill[d0], 1);
        pack[pos] = make_int2(s0, __float_as_int(dinv[s0] * w[e] * dinv[d0]));
    }
}

// ---------------- GEMM: C[N,64] = A[N,64] @ W[64,64] (fp32 vector) ----------------
__global__ __launch_bounds__(256) void k_gemm(const float* __restrict__ A,
                                              const float* __restrict__ W,
                                              float* __restrict__ C, int N) {
    __shared__ float sW[64 * 64];
    __shared__ float sA[64 * 64];
    int t = threadIdx.x;
    int rb = blockIdx.x * 64;
    #pragma unroll
    for (int i = 0; i < 16; i++) sW[t + 256 * i] = W[t + 256 * i];
    #pragma unroll
    for (int i = 0; i < 16; i++) {
        int idx = t + 256 * i;
        int r = rb + (idx >> 6);
        sA[idx] = (r < N) ? A[(size_t)r * D + (idx & 63)] : 0.0f;
    }
    __syncthreads();
    int tx = t & 15, ty = t >> 4;           // 16x16 threads, 4x4 micro-tile
    float acc[4][4] = {};
    #pragma unroll
    for (int k = 0; k < 64; k++) {
        float4 wv = *(const float4*)&sW[k * 64 + tx * 4];
        float h0 = sA[(ty * 4 + 0) * 64 + k];
        float h1 = sA[(ty * 4 + 1) * 64 + k];
        float h2 = sA[(ty * 4 + 2) * 64 + k];
        float h3 = sA[(ty * 4 + 3) * 64 + k];
        acc[0][0] += h0 * wv.x; acc[0][1] += h0 * wv.y; acc[0][2] += h0 * wv.z; acc[0][3] += h0 * wv.w;
        acc[1][0] += h1 * wv.x; acc[1][1] += h1 * wv.y; acc[1][2] += h1 * wv.z; acc[1][3] += h1 * wv.w;
        acc[2][0] += h2 * wv.x; acc[2][1] += h2 * wv.y; acc[2][2] += h2 * wv.z; acc[2][3] += h2 * wv.w;
        acc[3][0] += h3 * wv.x; acc[3][1] += h3 * wv.y; acc[3][2] += h3 * wv.z; acc[3][3] += h3 * wv.w;
    }
    #pragma unroll
    for (int i = 0; i < 4; i++) {
        int r = rb + ty * 4 + i;
        if (r < N) {
            float4 o = make_float4(acc[i][0], acc[i][1], acc[i][2], acc[i][3]);
            *(float4*)&C[(size_t)r * D + tx * 4] = o;
        }
    }
}

// ---------------- aggregate: deep-MLP gather ----------------
// one wave per dst node. Phase 1: ONE wave-wide load stages up to 64 pack
// entries to LDS (wave-internal, no barrier). Phase 2: 16 edges/iter ->
// 4 independent row-gather instructions in flight, 4 accumulators.
// grp = lane>>4 picks edge-in-quad; 16 lanes x float4 cover one 256B row.
template <int RELU>
__global__ __launch_bounds__(256) void k_agg(const float* __restrict__ hW,
                                             const int* __restrict__ rp,
                                             const int* __restrict__ cnt,
                                             const int2* __restrict__ pack,
                                             const float* __restrict__ dinv,
                                             const float* __restrict__ bias,
                                             float* __restrict__ hout, int N) {
    __shared__ int2 sp[4][64];
    int lane = threadIdx.x & 63;
    int widx = threadIdx.x >> 6;
    int n = blockIdx.x * 4 + widx;
    if (n >= N) return;
    int grp = lane >> 4;                  // 0..3
    int ch4 = (lane & 15) << 2;           // channel offset (float)
    int r0 = rp[n];
    int cg = (cnt[n] + 15) & ~15;
    // hoisted: overlap with edge gathers
    float dv = dinv[n];
    float4 sf = *(const float4*)&hW[(size_t)n * D + ch4];
    float4 bv = *(const float4*)&bias[ch4];
    float4 a0 = {0.f,0.f,0.f,0.f}, a1 = {0.f,0.f,0.f,0.f};
    float4 a2 = {0.f,0.f,0.f,0.f}, a3 = {0.f,0.f,0.f,0.f};
    for (int base = 0; base < cg; base += 64) {
        int rem = cg - base;              // multiple of 16
        int2 pk = make_int2(0, 0);
        if (lane < rem) pk = pack[r0 + base + lane];   // 64 edges, 1 instr
        sp[widx][lane] = pk;              // same-wave LDS: ordered, no barrier
        int m = rem < 64 ? rem : 64;
        for (int k = 0; k < m; k += 16) {
            int2 p0 = sp[widx][k + grp];
            int2 p1 = sp[widx][k + 4 + grp];
            int2 p2 = sp[widx][k + 8 + grp];
            int2 p3 = sp[widx][k + 12 + grp];
            const float4 r0v = *(const float4*)&hW[(size_t)p0.x * D + ch4];
            const float4 r1v = *(const float4*)&hW[(size_t)p1.x * D + ch4];
            const float4 r2v = *(const float4*)&hW[(size_t)p2.x * D + ch4];
            const float4 r3v = *(const float4*)&hW[(size_t)p3.x * D + ch4];
            float v0 = __int_as_float(p0.y), v1 = __int_as_float(p1.y);
            float v2 = __int_as_float(p2.y), v3 = __int_as_float(p3.y);
            a0.x += v0 * r0v.x; a0.y += v0 * r0v.y; a0.z += v0 * r0v.z; a0.w += v0 * r0v.w;
            a1.x += v1 * r1v.x; a1.y += v1 * r1v.y; a1.z += v1 * r1v.z; a1.w += v1 * r1v.w;
            a2.x += v2 * r2v.x; a2.y += v2 * r2v.y; a2.z += v2 * r2v.z; a2.w += v2 * r2v.w;
            a3.x += v3 * r3v.x; a3.y += v3 * r3v.y; a3.z += v3 * r3v.z; a3.w += v3 * r3v.w;
        }
    }
    float4 p;
    p.x = (a0.x + a1.x) + (a2.x + a3.x);
    p.y = (a0.y + a1.y) + (a2.y + a3.y);
    p.z = (a0.z + a1.z) + (a2.z + a3.z);
    p.w = (a0.w + a1.w) + (a2.w + a3.w);
    p.x += __shfl_xor(p.x, 16); p.y += __shfl_xor(p.y, 16);
    p.z += __shfl_xor(p.z, 16); p.w += __shfl_xor(p.w, 16);
    p.x += __shfl_xor(p.x, 32); p.y += __shfl_xor(p.y, 32);
    p.z += __shfl_xor(p.z, 32); p.w += __shfl_xor(p.w, 32);
    if (grp == 0) {                       // lanes 0..15 hold+store the row
        float s2 = dv * dv;
        float4 o;
        o.x = p.x + s2 * sf.x + bv.x;
        o.y = p.y + s2 * sf.y + bv.y;
        o.z = p.z + s2 * sf.z + bv.z;
        o.w = p.w + s2 * sf.w + bv.w;
        if (RELU) {
            o.x = fmaxf(o.x, 0.f); o.y = fmaxf(o.y, 0.f);
            o.z = fmaxf(o.z, 0.f); o.w = fmaxf(o.w, 0.f);
        }
        *(float4*)&hout[(size_t)n * D + ch4] = o;
    }
}

// ---------------- final layer: aggregate + MLP readout + graph-sum ----------------
__global__ __launch_bounds__(256) void k_agg_readout(const float* __restrict__ hW,
                                                     const int* __restrict__ rp,
                                                     const int* __restrict__ cnt,
                                                     const int2* __restrict__ pack,
                                                     const float* __restrict__ dinv,
                                                     const float* __restrict__ bias,
                                                     const float* __restrict__ RW1,
                                                     const float* __restrict__ Rb1,
                                                     const float* __restrict__ RW2,
                                                     const float* __restrict__ Rb2,
                                                     const int* __restrict__ batch,
                                                     float* __restrict__ gsum, int N) {
    __shared__ int2 sp[4][64];
    __shared__ float sh[4][64];
    int lane = threadIdx.x & 63;
    int widx = threadIdx.x >> 6;
    int n = blockIdx.x * 4 + widx;
    if (n >= N) return;                   // all LDS traffic is wave-internal
    int grp = lane >> 4;
    int ch4 = (lane & 15) << 2;
    int r0 = rp[n];
    int cg = (cnt[n] + 15) & ~15;
    float dv = dinv[n];
    float4 sf = *(const float4*)&hW[(size_t)n * D + ch4];
    float4 bv = *(const float4*)&bias[ch4];
    float4 a0 = {0.f,0.f,0.f,0.f}, a1 = {0.f,0.f,0.f,0.f};
    float4 a2 = {0.f,0.f,0.f,0.f}, a3 = {0.f,0.f,0.f,0.f};
    for (int base = 0; base < cg; base += 64) {
        int rem = cg - base;
        int2 pk = make_int2(0, 0);
        if (lane < rem) pk = pack[r0 + base + lane];
        sp[widx][lane] = pk;
        int m = rem < 64 ? rem : 64;
        for (int k = 0; k < m; k += 16) {
            int2 p0 = sp[widx][k + grp];
            int2 p1 = sp[widx][k + 4 + grp];
            int2 p2 = sp[widx][k + 8 + grp];
            int2 p3 = sp[widx][k + 12 + grp];
            const float4 r0v = *(const float4*)&hW[(size_t)p0.x * D + ch4];
            const float4 r1v = *(const float4*)&hW[(size_t)p1.x * D + ch4];
            const float4 r2v = *(const float4*)&hW[(size_t)p2.x * D + ch4];
            const float4 r3v = *(const float4*)&hW[(size_t)p3.x * D + ch4];
            float v0 = __int_as_float(p0.y), v1 = __int_as_float(p1.y);
            float v2 = __int_as_float(p2.y), v3 = __int_as_float(p3.y);
            a0.x += v0 * r0v.x; a0.y += v0 * r0v.y; a0.z += v0 * r0v.z; a0.w += v0 * r0v.w;
            a1.x += v1 * r1v.x; a1.y += v1 * r1v.y; a1.z += v1 * r1v.z; a1.w += v1 * r1v.w;
            a2.x += v2 * r2v.x; a2.y += v2 * r2v.y; a2.z += v2 * r2v.z; a2.w += v2 * r2v.w;
            a3.x += v3 * r3v.x; a3.y += v3 * r3v.y; a3.z += v3 * r3v.z; a3.w += v3 * r3v.w;
        }
    }
    float4 p;
    p.x = (a0.x + a1.x) + (a2.x + a3.x);
    p.y = (a0.y + a1.y) + (a2.y + a3.y);
    p.z = (a0.z + a1.z) + (a2.z + a3.z);
    p.w = (a0.w + a1.w) + (a2.w + a3.w);
    p.x += __shfl_xor(p.x, 16); p.y += __shfl_xor(p.y, 16);
    p.z += __shfl_xor(p.z, 16); p.w += __shfl_xor(p.w, 16);
    p.x += __shfl_xor(p.x, 32); p.y += __shfl_xor(p.y, 32);
    p.z += __shfl_xor(p.z, 32); p.w += __shfl_xor(p.w, 32);
    if (grp == 0) {
        float s2 = dv * dv;
        float4 o;                          // h2: no relu on last GCN layer
        o.x = p.x + s2 * sf.x + bv.x;
        o.y = p.y + s2 * sf.y + bv.y;
        o.z = p.z + s2 * sf.z + bv.z;
        o.w = p.w + s2 * sf.w + bv.w;
        *(float4*)&sh[widx][ch4] = o;
    }
    // MLP: all 64 lanes. unit = lane&31, half = lane>>5 covers 32 cc each.
    int unit = lane & 31, half = lane >> 5;
    float m = 0.0f;
    #pragma unroll
    for (int j = 0; j < 32; j++) {
        int cc = half * 32 + j;
        m += sh[widx][cc] * RW1[cc * 32 + unit];
    }
    m += __shfl_xor(m, 32);               // combine the two cc-halves
    m += Rb1[unit];
    m = fmaxf(m, 0.0f);
    float y = m * RW2[unit];
    #pragma unroll
    for (int off = 16; off >= 1; off >>= 1) y += __shfl_xor(y, off);
    if (lane == 0) atomicAdd(&gsum[batch[n]], y + Rb2[0]);
}

// ---------------- scatter-mean finalize ----------------
__global__ __launch_bounds__(256) void k_final(const float* __restrict__ gsum,
                                               const int* __restrict__ gcnt,
                                               float* __restrict__ out, int G) {
    int g = blockIdx.x * 256 + threadIdx.x;
    if (g < G) out[g] = gsum[g] / fmaxf((float)gcnt[g], 1.0f);
}

extern "C" void kernel_launch(void* const* d_in, const int* in_sizes, int n_in,
                              void* d_out, int out_size, void* d_ws, size_t ws_size,
                              hipStream_t stream) {
    const float* x     = (const float*)d_in[0];
    const int*   ei    = (const int*)d_in[1];
    const float* ea    = (const float*)d_in[2];
    const int*   batch = (const int*)d_in[3];
    const float* W0 = (const float*)d_in[4];
    const float* b0 = (const float*)d_in[5];
    const float* W1 = (const float*)d_in[6];
    const float* b1 = (const float*)d_in[7];
    const float* W2 = (const float*)d_in[8];
    const float* b2 = (const float*)d_in[9];
    const float* RW1 = (const float*)d_in[10];
    const float* Rb1 = (const float*)d_in[11];
    const float* RW2 = (const float*)d_in[12];
    const float* Rb2 = (const float*)d_in[13];

    const int N = in_sizes[0] / D;        // 100000
    const int E = in_sizes[1] / 2;        // 1200000
    const int G = out_size;               // 512
    const int* src = ei;
    const int* dst = ei + E;

    const size_t EP = (size_t)E + 16 * (size_t)N;  // padded CSR capacity (x16 groups)

    // ---- workspace layout ----
    char* p = (char*)d_ws;
    // zero-init region (one memset): deg, cnt, fill, gsum, gcnt, pack
    float* deg   = (float*)p;             p += (size_t)N * 4;
    int*   cnt   = (int*)p;               p += (size_t)N * 4;
    int*   fill  = (int*)p;               p += (size_t)N * 4;
    float* gsum  = (float*)p;             p += (size_t)NG * 4;
    int*   gcnt  = (int*)p;               p += (size_t)NG * 4;
    int2*  pack  = (int2*)p;              p += EP * 8;
    size_t zbytes = (size_t)(3 * N + 2 * NG) * 4 + EP * 8;
    // no-init region
    float* dinv  = (float*)p;             p += (size_t)N * 4;
    int*   rp    = (int*)p;               p += (size_t)N * 4;
    int*   bsums = (int*)p;               p += (size_t)512 * 4;
    float* hW    = (float*)p;             p += (size_t)N * D * 4;
    float* h     = (float*)p;             p += (size_t)N * D * 4;

    hipMemsetAsync(d_ws, 0, zbytes, stream);

    int ebl = (E + 255) / 256;
    int nbl = (N + 255) / 256;            // 391
    k_edge_deg<<<ebl, 256, 0, stream>>>(src, dst, ea, deg, cnt, E);
    k_node_dinv<<<nbl, 256, 0, stream>>>(deg, dinv, batch, gcnt, N);
    k_scan1<<<nbl, 256, 0, stream>>>(cnt, rp, bsums, N);
    k_scan2<<<1, 512, 0, stream>>>(bsums, nbl);
    k_scan3<<<nbl, 256, 0, stream>>>(rp, bsums, N);
    k_fill<<<ebl, 256, 0, stream>>>(src, dst, ea, dinv, rp, fill, pack, E);

    int gemm_bl = (N + 63) / 64;          // 1563
    int agg_bl  = (N + 3) / 4;            // 25000

    // layer 0: x -> h
    k_gemm<<<gemm_bl, 256, 0, stream>>>(x, W0, hW, N);
    k_agg<1><<<agg_bl, 256, 0, stream>>>(hW, rp, cnt, pack, dinv, b0, h, N);
    // layer 1: h -> h
    k_gemm<<<gemm_bl, 256, 0, stream>>>(h, W1, hW, N);
    k_agg<1><<<agg_bl, 256, 0, stream>>>(hW, rp, cnt, pack, dinv, b1, h, N);
    // layer 2 + readout + graph scatter
    k_gemm<<<gemm_bl, 256, 0, stream>>>(h, W2, hW, N);
    k_agg_readout<<<agg_bl, 256, 0, stream>>>(hW, rp, cnt, pack, dinv, b2,
                                              RW1, Rb1, RW2, Rb2, batch, gsum, N);

    k_final<<<(G + 255) / 256, 256, 0, stream>>>(gsum, gcnt, (float*)d_out, G);
}